// Round 4
// baseline (754.182 us; speedup 1.0000x reference)
//
#include <hip/hip_runtime.h>
#include <cstdint>
#include <cstddef>

#define B_ROWS 65536
#define DMODEL 2048
#define NEXP 64
#define TOPK 8
#define ROWS_PER_BLK 64
#define NBLK (B_ROWS / ROWS_PER_BLK)   // 1024
#define THREADS 256                    // 4 waves, split-D x4
#define WSLICE (DMODEL / 4)            // 512 dds per wave
#define DC 8                           // dds per staged chunk
#define NCH (WSLICE / DC)              // 64
#define SLAB 68                        // slab row stride (float4-aligned)
#define GOFF ((size_t)B_ROWS * NEXP)
#define AUX_OFF ((size_t)B_ROWS * NEXP + (size_t)B_ROWS * TOPK)

#define GLOAD16(g, l)                                                      \
  __builtin_amdgcn_global_load_lds(                                       \
      (const __attribute__((address_space(1))) void*)(g),                 \
      (__attribute__((address_space(3))) void*)(l), 16, 0, 0)

__global__ __launch_bounds__(THREADS, 3) void router_main(
    const float* __restrict__ x, const float* __restrict__ W,
    const float* __restrict__ bias, float* __restrict__ out,
    float* __restrict__ ws)
{
  // union: staging 4 waves x 2048 floats (x dbuf 2x512 + W dbuf 2x512)
  //        vs epilogue slab 4 x 32 x 68 = 8704 floats. Barrier-separated.
  __shared__ float lds[4 * 32 * SLAB];
  __shared__ float idxb[32 * TOPK];

  const int tid = threadIdx.x;
  const int lane = tid & 63;
  const int w = tid >> 6;          // wave = D-slice 0..3
  const int eg = lane & 7;         // expert group (8 experts each)
  const int rg = lane >> 3;        // row group (8 rows each)
  const size_t row0 = (size_t)blockIdx.x * ROWS_PER_BLK;
  const int dbase = w * WSLICE;

  float* stg = lds + w * 2048;     // this wave's staging area

  float acc[8][8];
#pragma unroll
  for (int r = 0; r < 8; ++r)
#pragma unroll
    for (int e = 0; e < 8; ++e) acc[r][e] = 0.f;

  // x staging: LDS slot (i*64+L) must hold row srow(L) = inverse of the
  // read-side XOR swizzle (involution): srow = (L&~7) | ((L ^ (L>>3)) & 7)
  const int srow = (lane & ~7) | ((lane ^ (lane >> 3)) & 7);
  const float* xsrc = x + (row0 + srow) * DMODEL + dbase;
  const float* wsrc = W + (size_t)dbase * NEXP + lane * 4;

#define STAGE(c, b)                                                        \
  do {                                                                     \
    float* xb_ = stg + (b) * 512;                                          \
    float* wb_ = stg + 1024 + (b) * 512;                                   \
    GLOAD16(xsrc + (c) * DC + 0, xb_ + 0);                                 \
    GLOAD16(xsrc + (c) * DC + 4, xb_ + 256);                               \
    GLOAD16(wsrc + (c) * 512 + 0, wb_ + 0);                                \
    GLOAD16(wsrc + (c) * 512 + 256, wb_ + 256);                            \
  } while (0)

  // swizzled x-read bases: slot = i*64 + rg*8 + (rr^rg), float off = slot*4
  int xsw[8];
#pragma unroll
  for (int rr = 0; rr < 8; ++rr) xsw[rr] = rg * 32 + ((rr ^ rg) << 2);
  const int wboff = eg * 8;

  STAGE(0, 0);
  for (int c = 0; c < NCH; ++c) {
    __syncthreads();                 // drains stage(c); frees buf (c+1)&1
    if (c + 1 < NCH) STAGE(c + 1, (c + 1) & 1);
    const float* xb = stg + (c & 1) * 512;
    const float* wb = stg + 1024 + (c & 1) * 512;
#pragma unroll
    for (int i = 0; i < 2; ++i) {
      float4 xv[8];
#pragma unroll
      for (int rr = 0; rr < 8; ++rr)
        xv[rr] = *(const float4*)(xb + i * 256 + xsw[rr]);
#pragma unroll
      for (int ddl = 0; ddl < 4; ++ddl) {
        const float* wp = wb + (i * 4 + ddl) * NEXP + wboff;
        float4 wlo = *(const float4*)(wp);
        float4 whi = *(const float4*)(wp + 4);
#pragma unroll
        for (int rr = 0; rr < 8; ++rr) {
          float xs_ = (ddl == 0) ? xv[rr].x : (ddl == 1) ? xv[rr].y
                     : (ddl == 2) ? xv[rr].z : xv[rr].w;
          acc[rr][0] = fmaf(xs_, wlo.x, acc[rr][0]);
          acc[rr][1] = fmaf(xs_, wlo.y, acc[rr][1]);
          acc[rr][2] = fmaf(xs_, wlo.z, acc[rr][2]);
          acc[rr][3] = fmaf(xs_, wlo.w, acc[rr][3]);
          acc[rr][4] = fmaf(xs_, whi.x, acc[rr][4]);
          acc[rr][5] = fmaf(xs_, whi.y, acc[rr][5]);
          acc[rr][6] = fmaf(xs_, whi.z, acc[rr][6]);
          acc[rr][7] = fmaf(xs_, whi.w, acc[rr][7]);
        }
      }
    }
  }

  // ---------------- epilogue: two 32-row phases ----------------
  float accF = 0.f, accP = 0.f;   // lane = expert totals (wave 0)

  for (int h = 0; h < 2; ++h) {
    __syncthreads();   // staging (h=0) / previous coop reads (h=1) done
    if ((rg >> 2) == h) {
      const int lr = (rg & 3) * 8;
#pragma unroll
      for (int rr = 0; rr < 8; ++rr) {
        float* d = lds + w * (32 * SLAB) + (lr + rr) * SLAB + eg * 8;
        *(float4*)(d + 0) = make_float4(acc[rr][0], acc[rr][1], acc[rr][2], acc[rr][3]);
        *(float4*)(d + 4) = make_float4(acc[rr][4], acc[rr][5], acc[rr][6], acc[rr][7]);
      }
    }
    __syncthreads();

    if (w == 0) {
      const bool valid = lane < 32;
      const int lr = lane & 31;
      float a[NEXP];
#pragma unroll
      for (int n = 0; n < NEXP; ++n)
        a[n] = ((lds[0 * (32 * SLAB) + lr * SLAB + n]
               + lds[1 * (32 * SLAB) + lr * SLAB + n])
               + lds[2 * (32 * SLAB) + lr * SLAB + n])
               + lds[3 * (32 * SLAB) + lr * SLAB + n];

      // top-8 by biased logits; strict > keeps lowest index on ties
      unsigned long long sel = 0ull;
      int idx[TOPK];
      float selu[TOPK];
#pragma unroll
      for (int k = 0; k < TOPK; ++k) {
        float best = -INFINITY, bestu = 0.f;
        int bi = 0;
#pragma unroll
        for (int n = 0; n < NEXP; ++n) {
          float vb = a[n] + bias[n];
          bool taken = (sel >> n) & 1ull;
          vb = taken ? -INFINITY : vb;
          if (vb > best) { best = vb; bestu = a[n]; bi = n; }
        }
        sel |= 1ull << bi;
        idx[k] = bi;
        selu[k] = bestu;
      }

      float mx = selu[0];
#pragma unroll
      for (int k = 1; k < TOPK; ++k) mx = fmaxf(mx, selu[k]);
      float g[TOPK]; float gs = 0.f;
#pragma unroll
      for (int k = 0; k < TOPK; ++k) { g[k] = __expf(selu[k] - mx); gs += g[k]; }
      float ginv = 1.f / gs;

      // gates row -> slab0 (own row only; read-before-write per lane)
      if (valid) {
#pragma unroll
        for (int n = 0; n < NEXP; ++n) {
          float gv = 0.f;
#pragma unroll
          for (int k = 0; k < TOPK; ++k) gv = (idx[k] == n) ? g[k] * ginv : gv;
          lds[lr * SLAB + n] = gv;
        }
#pragma unroll
        for (int k = 0; k < TOPK; ++k) idxb[lr * TOPK + k] = (float)idx[k];
      }

      // P_i softmax over all 64 logits; F_i via ballot. All 64 lanes active.
      float m2 = -INFINITY;
#pragma unroll
      for (int n = 0; n < NEXP; ++n) m2 = fmaxf(m2, a[n]);
      float s2 = 0.f;
#pragma unroll
      for (int n = 0; n < NEXP; ++n) s2 += __expf(a[n] - m2);
      float pinv = 1.f / s2;
#pragma unroll
      for (int n = 0; n < NEXP; ++n) {
        float v = valid ? __expf(a[n] - m2) * pinv : 0.f;
        v += __shfl_xor(v, 1);
        v += __shfl_xor(v, 2);
        v += __shfl_xor(v, 4);
        v += __shfl_xor(v, 8);
        v += __shfl_xor(v, 16);
        v += __shfl_xor(v, 32);
        unsigned long long b = __ballot(valid && ((sel >> n) & 1ull));
        if (lane == n) { accP += v; accF += (float)__popcll(b); }
      }
    }
    __syncthreads();   // slab0 gates + idxb ready

    if (w == 0) {
      // coalesced gates write: 32 rows x 64 = 512 float4
      float* gout = out + (row0 + h * 32) * NEXP;
#pragma unroll
      for (int t = 0; t < 8; ++t) {
        int f = t * 64 + lane;
        int r = f >> 4, c4 = (f & 15) * 4;
        float4 v = *(const float4*)(lds + r * SLAB + c4);
        *(float4*)(gout + r * NEXP + c4) = v;
      }
      // coalesced indices write: 256 floats = 64 float4
      float4 iv = *(const float4*)(idxb + (lane >> 1) * TOPK + (lane & 1) * 4);
      *(float4*)(out + GOFF + (row0 + h * 32) * TOPK + lane * 4) = iv;
    }
  }

  if (w == 0) {
    ws[(size_t)blockIdx.x * (2 * NEXP) + lane] = accF;
    ws[(size_t)blockIdx.x * (2 * NEXP) + NEXP + lane] = accP;
  }
}

// deterministic final reduction over the 1024 block partials
__global__ __launch_bounds__(256) void router_aux(
    const float* __restrict__ ws, float* __restrict__ out)
{
  __shared__ float sf[4][NEXP];
  __shared__ float sp[4][NEXP];
  int t = threadIdx.x;
  int n = t & 63, part = t >> 6;
  float f = 0.f, p = 0.f;
#pragma unroll 8
  for (int b = part; b < NBLK; b += 4) {
    f += ws[(size_t)b * (2 * NEXP) + n];
    p += ws[(size_t)b * (2 * NEXP) + NEXP + n];
  }
  sf[part][n] = f;
  sp[part][n] = p;
  __syncthreads();
  if (t < NEXP) {
    float F = sf[0][t] + sf[1][t] + sf[2][t] + sf[3][t];
    float P = sp[0][t] + sp[1][t] + sp[2][t] + sp[3][t];
    float v = F * P;
    v += __shfl_xor(v, 1);
    v += __shfl_xor(v, 2);
    v += __shfl_xor(v, 4);
    v += __shfl_xor(v, 8);
    v += __shfl_xor(v, 16);
    v += __shfl_xor(v, 32);
    if (t == 0)
      out[AUX_OFF] = 0.01f * 64.f * v / (4294967296.0f /* 65536^2 */);
  }
}

extern "C" void kernel_launch(void* const* d_in, const int* in_sizes, int n_in,
                              void* d_out, int out_size, void* d_ws, size_t ws_size,
                              hipStream_t stream) {
  const float* x = (const float*)d_in[0];
  const float* W = (const float*)d_in[1];
  const float* bias = (const float*)d_in[2];
  float* out = (float*)d_out;
  float* ws = (float*)d_ws;
  router_main<<<NBLK, THREADS, 0, stream>>>(x, W, bias, out, ws);
  router_aux<<<1, 256, 0, stream>>>(ws, out);
}

// Round 5
// 458.386 us; speedup vs baseline: 1.6453x; 1.6453x over previous
//
#include <hip/hip_runtime.h>
#include <cstdint>
#include <cstddef>

#define B_ROWS 65536
#define DMODEL 2048
#define NEXP 64
#define TOPK 8
#define WAVES 2
#define THREADS 128                    // 2 waves; 64 rows per wave
#define ROWS_PER_BLK 128
#define NBLK (B_ROWS / ROWS_PER_BLK)   // 512 blocks = 2 per CU
#define DC 16                          // dds per staged chunk
#define NCH (DMODEL / DC)              // 128
#define SLAB 65
#define GOFF ((size_t)B_ROWS * NEXP)
#define AUX_OFF (GOFF + (size_t)B_ROWS * TOPK)

#define GLOAD16(g, l)                                                      \
  __builtin_amdgcn_global_load_lds(                                       \
      (const __attribute__((address_space(1))) void*)(g),                 \
      (__attribute__((address_space(3))) void*)(l), 16, 0, 0)

__global__ __launch_bounds__(THREADS, 2) void router_main(
    const float* __restrict__ x, const float* __restrict__ W,
    const float* __restrict__ bias, float* __restrict__ out,
    float* __restrict__ ws)
{
  // LDS (floats): loop phase: x dbuf 2x[2 waves][64][16] = 4096,
  //               W dbuf 2x[16][64] = 2048  (total 6144)
  // epilogue:     slab [2 waves][64][65] = 8320 + redF/redP 256 = 8576.
  __shared__ float lds[8576];

  const int tid = threadIdx.x;
  const int lane = tid & 63;
  const int w = tid >> 6;
  const int eg = lane & 7;        // expert group (8 experts)
  const int rg = lane >> 3;       // row group (8 rows)
  const size_t row0 = (size_t)blockIdx.x * ROWS_PER_BLK;
  const size_t wrow0 = row0 + (size_t)w * 64;

  float* xb0 = lds + w * 1024;
  float* xb1 = lds + 2048 + w * 1024;
  float* wb0 = lds + 4096;
  float* wb1 = lds + 5120;

  float acc[8][8];
#pragma unroll
  for (int r = 0; r < 8; ++r)
#pragma unroll
    for (int e = 0; e < 8; ++e) acc[r][e] = 0.f;

  // x staging: instr i covers rows 16i..16i+15; lane l -> row l>>2, 16B col l&3.
  // 16 lanes read 64B contiguous per row -> coalesced; LDS linear [row][16].
  const float* xsrc = x + (wrow0 + (size_t)(lane >> 2)) * DMODEL + (lane & 3) * 4;
  // W chunk = 4KB contiguous; wave w stages half via 2 instrs. Linear [16][64].
  const float* wsrc = W + (size_t)w * 512 + (size_t)lane * 4;

#define STAGE(c, xb_, wb_)                                                 \
  do {                                                                     \
    const float* xs_ = xsrc + (size_t)(c) * DC;                            \
    GLOAD16(xs_ + 0 * 16 * DMODEL, (xb_) + 0 * 256);                       \
    GLOAD16(xs_ + 1 * 16 * DMODEL, (xb_) + 1 * 256);                       \
    GLOAD16(xs_ + 2 * 16 * DMODEL, (xb_) + 2 * 256);                       \
    GLOAD16(xs_ + 3 * 16 * DMODEL, (xb_) + 3 * 256);                       \
    const float* ws_ = wsrc + (size_t)(c) * 1024;                          \
    GLOAD16(ws_ + 0,   (wb_) + w * 512 + 0);                               \
    GLOAD16(ws_ + 256, (wb_) + w * 512 + 256);                             \
  } while (0)

  STAGE(0, xb0, wb0);
  for (int c = 0; c < NCH; ++c) {
    __syncthreads();                       // buf (c&1) ready; buf ((c+1)&1) free
    if (c + 1 < NCH) {
      if (c & 1) STAGE(c + 1, xb0, wb0);   // overlaps compute below
      else       STAGE(c + 1, xb1, wb1);
    }
    const float* xw = ((c & 1) ? xb1 : xb0) + rg * 128;   // [8 rows][16]
    const float* wg = ((c & 1) ? wb1 : wb0) + eg * 8;
#pragma unroll
    for (int d4 = 0; d4 < 4; ++d4) {
      float4 xv[8];
#pragma unroll
      for (int rr = 0; rr < 8; ++rr)
        xv[rr] = *(const float4*)(xw + rr * 16 + d4 * 4);  // 2-way max (bcast)
#pragma unroll
      for (int k = 0; k < 4; ++k) {
        const float* wp = wg + (d4 * 4 + k) * 64;
        float4 wlo = *(const float4*)(wp);                 // 2-way max (bcast)
        float4 whi = *(const float4*)(wp + 4);
#pragma unroll
        for (int rr = 0; rr < 8; ++rr) {
          float xs_ = (k == 0) ? xv[rr].x : (k == 1) ? xv[rr].y
                     : (k == 2) ? xv[rr].z : xv[rr].w;
          acc[rr][0] = fmaf(xs_, wlo.x, acc[rr][0]);
          acc[rr][1] = fmaf(xs_, wlo.y, acc[rr][1]);
          acc[rr][2] = fmaf(xs_, wlo.z, acc[rr][2]);
          acc[rr][3] = fmaf(xs_, wlo.w, acc[rr][3]);
          acc[rr][4] = fmaf(xs_, whi.x, acc[rr][4]);
          acc[rr][5] = fmaf(xs_, whi.y, acc[rr][5]);
          acc[rr][6] = fmaf(xs_, whi.z, acc[rr][6]);
          acc[rr][7] = fmaf(xs_, whi.w, acc[rr][7]);
        }
      }
    }
  }
  __syncthreads();   // staging dead; slab region becomes live

  // ---- transpose acc -> slab[row][expert] (wave-private region) ----
  float* slab = lds + w * (64 * SLAB);
#pragma unroll
  for (int rr = 0; rr < 8; ++rr) {
    float* d = slab + (rg * 8 + rr) * SLAB + eg * 8;
    *(float4*)(d + 0) = make_float4(acc[rr][0], acc[rr][1], acc[rr][2], acc[rr][3]);
    *(float4*)(d + 4) = make_float4(acc[rr][4], acc[rr][5], acc[rr][6], acc[rr][7]);
  }
  __syncthreads();

  // ---------------- epilogue: lane = row (64 rows per wave) ----------------
  float a[NEXP];
#pragma unroll
  for (int n = 0; n < NEXP; ++n) a[n] = slab[lane * SLAB + n];

  // top-8 by biased logits; strict > keeps lowest index on ties
  unsigned long long sel = 0ull;
  int idx[TOPK];
  float selu[TOPK];
#pragma unroll
  for (int k = 0; k < TOPK; ++k) {
    float best = -INFINITY, bestu = 0.f;
    int bi = 0;
#pragma unroll
    for (int n = 0; n < NEXP; ++n) {
      float vb = a[n] + bias[n];
      bool taken = (sel >> n) & 1ull;
      vb = taken ? -INFINITY : vb;
      if (vb > best) { best = vb; bestu = a[n]; bi = n; }
    }
    sel |= 1ull << bi;
    idx[k] = bi;
    selu[k] = bestu;
  }

  float mx = selu[0];
#pragma unroll
  for (int k = 1; k < TOPK; ++k) mx = fmaxf(mx, selu[k]);
  float g[TOPK]; float gs = 0.f;
#pragma unroll
  for (int k = 0; k < TOPK; ++k) { g[k] = __expf(selu[k] - mx); gs += g[k]; }
  float ginv = 1.f / gs;

  // gates: each lane writes its own row (16 float4 stores)
  float* grow = out + (wrow0 + lane) * NEXP;
#pragma unroll
  for (int n4 = 0; n4 < 16; ++n4) {
    float gv[4];
#pragma unroll
    for (int j = 0; j < 4; ++j) {
      int n = n4 * 4 + j;
      float v = 0.f;
#pragma unroll
      for (int k = 0; k < TOPK; ++k) v = (idx[k] == n) ? g[k] * ginv : v;
      gv[j] = v;
    }
    *(float4*)(grow + n4 * 4) = make_float4(gv[0], gv[1], gv[2], gv[3]);
  }

  // indices as float32 (2 float4 stores)
  float* irow = out + GOFF + (wrow0 + lane) * TOPK;
  *(float4*)(irow + 0) = make_float4((float)idx[0], (float)idx[1], (float)idx[2], (float)idx[3]);
  *(float4*)(irow + 4) = make_float4((float)idx[4], (float)idx[5], (float)idx[6], (float)idx[7]);

  // P_i softmax over all 64 logits; F_i via ballot
  float m2 = -INFINITY;
#pragma unroll
  for (int n = 0; n < NEXP; ++n) m2 = fmaxf(m2, a[n]);
  float s2 = 0.f;
#pragma unroll
  for (int n = 0; n < NEXP; ++n) s2 += __expf(a[n] - m2);
  float pinv = 1.f / s2;

  float myP = 0.f, myF = 0.f;
#pragma unroll
  for (int n = 0; n < NEXP; ++n) {
    float v = __expf(a[n] - m2) * pinv;
    v += __shfl_xor(v, 1);
    v += __shfl_xor(v, 2);
    v += __shfl_xor(v, 4);
    v += __shfl_xor(v, 8);
    v += __shfl_xor(v, 16);
    v += __shfl_xor(v, 32);
    unsigned long long b = __ballot((sel >> n) & 1ull);
    if (lane == n) { myP = v; myF = (float)__popcll(b); }
  }
  float* redF = lds + WAVES * 64 * SLAB;        // 128 floats
  float* redP = redF + WAVES * 64;              // 128 floats
  redF[w * 64 + lane] = myF;
  redP[w * 64 + lane] = myP;
  __syncthreads();
  if (tid < NEXP) {
    float F = redF[tid] + redF[64 + tid];
    float P = redP[tid] + redP[64 + tid];
    ws[(size_t)blockIdx.x * (2 * NEXP) + tid] = F;
    ws[(size_t)blockIdx.x * (2 * NEXP) + NEXP + tid] = P;
  }
}

// deterministic final reduction over the 512 block partials
__global__ __launch_bounds__(256) void router_aux(
    const float* __restrict__ ws, float* __restrict__ out)
{
  __shared__ float sf[4][NEXP];
  __shared__ float sp[4][NEXP];
  int t = threadIdx.x;
  int n = t & 63, part = t >> 6;
  float f = 0.f, p = 0.f;
#pragma unroll 8
  for (int b = part; b < NBLK; b += 4) {
    f += ws[(size_t)b * (2 * NEXP) + n];
    p += ws[(size_t)b * (2 * NEXP) + NEXP + n];
  }
  sf[part][n] = f;
  sp[part][n] = p;
  __syncthreads();
  if (t < NEXP) {
    float F = sf[0][t] + sf[1][t] + sf[2][t] + sf[3][t];
    float P = sp[0][t] + sp[1][t] + sp[2][t] + sp[3][t];
    float v = F * P;
    v += __shfl_xor(v, 1);
    v += __shfl_xor(v, 2);
    v += __shfl_xor(v, 4);
    v += __shfl_xor(v, 8);
    v += __shfl_xor(v, 16);
    v += __shfl_xor(v, 32);
    if (t == 0)
      out[AUX_OFF] = 0.01f * 64.f * v / (4294967296.0f /* 65536^2 */);
  }
}

extern "C" void kernel_launch(void* const* d_in, const int* in_sizes, int n_in,
                              void* d_out, int out_size, void* d_ws, size_t ws_size,
                              hipStream_t stream) {
  const float* x = (const float*)d_in[0];
  const float* W = (const float*)d_in[1];
  const float* bias = (const float*)d_in[2];
  float* out = (float*)d_out;
  float* ws = (float*)d_ws;
  router_main<<<NBLK, THREADS, 0, stream>>>(x, W, bias, out, ws);
  router_aux<<<1, 256, 0, stream>>>(ws, out);
}